// Round 4
// baseline (756.154 us; speedup 1.0000x reference)
//
#include <hip/hip_runtime.h>
#include <cstdint>

// Attention block: x(B=64,T=128,C=2048) fp32; H=16, hd=128.
// q=x@wq^T, k=x@wk^T, v=x@wv^T ; RoPE(q,k) ; causal softmax attn ; out@wo^T.
// bf16 MFMA; fp32 softmax; RoPE fused into attention kernel.
// R4: restructured GEMM K-loop — B direct global->reg (prefetched, no LDS),
//     A double-buffered LDS with prefetch issued top-of-phase / drained at
//     bottom barrier (loads stay in flight across a full compute phase).

typedef unsigned short ushort;
typedef __bf16 bf16x8 __attribute__((ext_vector_type(8)));
typedef float floatx4 __attribute__((ext_vector_type(4)));

__device__ __forceinline__ ushort f2bf(float f) {
  union { float f; uint32_t u; } v; v.f = f;
  uint32_t r = v.u + 0x7FFFu + ((v.u >> 16) & 1u);
  return (ushort)(r >> 16);
}
__device__ __forceinline__ float bf2f(ushort h) {
  union { uint32_t u; float f; } v; v.u = ((uint32_t)h) << 16;
  return v.f;
}

__device__ __forceinline__ void load_lds16(const void* g, void* l) {
  __builtin_amdgcn_global_load_lds(
      (__attribute__((address_space(1))) void*)(uintptr_t)g,
      (__attribute__((address_space(3))) void*)(uint32_t)(uintptr_t)l,
      16, 0, 0);
}

__device__ __forceinline__ void store_out(ushort* C, size_t i, float v) { C[i] = f2bf(v); }
__device__ __forceinline__ void store_out(float* C, size_t i, float v) { C[i] = v; }

// C[m,n] = sum_k A[m,k]*B[n,k].  128x128 tile, BK=32, 4 waves (2x2 of 64x64),
// 4x4 16x16x32 acc per wave. A staged in double-buffered LDS (XOR bank swizzle,
// global-side permute); B fragments loaded directly global->VGPR, one phase ahead.
template <typename OutT>
__device__ __forceinline__ void gemm_bt_body(const ushort* __restrict__ A,
                                             const ushort* __restrict__ B,
                                             OutT* __restrict__ C,
                                             int M, int N, int K) {
  __shared__ __align__(16) ushort As0[128 * 32];
  __shared__ __align__(16) ushort As1[128 * 32];
  const int tid = threadIdx.x;
  const int wave = tid >> 6, lane = tid & 63;
  const int quad = lane >> 4, colv = lane & 15;
  const int m0 = blockIdx.x * 128, n0 = blockIdx.y * 128;
  const int wm = (wave & 1) * 64, wn = (wave >> 1) * 64;

  floatx4 acc[4][4] = {};

  // A staging: thread tid covers LDS slot (row0=tid>>2, g=tid&3); fetches global
  // k-group g ^ ((row0>>1)&3). (row0+64 has the same XOR.)
  const int row0 = tid >> 2;
  const int c0 = ((tid & 3) ^ ((row0 >> 1) & 3)) * 8;
  const ushort* Ab1 = A + (size_t)(m0 + row0) * K + c0;
  const ushort* Ab2 = Ab1 + (size_t)64 * K;

  // Fragment read addresses (loop-invariant, swizzle-compensated).
  int aoff[4];
#pragma unroll
  for (int i = 0; i < 4; ++i) {
    int ra = wm + i * 16 + colv;
    aoff[i] = ra * 32 + ((quad ^ ((ra >> 1) & 3)) << 3);
  }

  // B fragment global pointers: row n = n0+wn+j*16+colv, k-offset quad*8.
  const ushort* Bp0 = B + (size_t)(n0 + wn + 0 + colv) * K + quad * 8;
  const ushort* Bp1 = B + (size_t)(n0 + wn + 16 + colv) * K + quad * 8;
  const ushort* Bp2 = B + (size_t)(n0 + wn + 32 + colv) * K + quad * 8;
  const ushort* Bp3 = B + (size_t)(n0 + wn + 48 + colv) * K + quad * 8;

  // Preload k=0: A -> As0, B -> b0.
  load_lds16(Ab1, &As0[wave * 512]);
  load_lds16(Ab2, &As0[wave * 512 + 2048]);
  bf16x8 b0[4], b1[4];
  b0[0] = *(const bf16x8*)Bp0;
  b0[1] = *(const bf16x8*)Bp1;
  b0[2] = *(const bf16x8*)Bp2;
  b0[3] = *(const bf16x8*)Bp3;
  __syncthreads();

  for (int k0 = 0; k0 < K; k0 += 64) {
    // phase 0: compute k0 from As0/b0; prefetch k0+32 -> As1/b1.
    {
      const int kn = k0 + 32;  // always < K (K % 64 == 0)
      load_lds16(Ab1 + kn, &As1[wave * 512]);
      load_lds16(Ab2 + kn, &As1[wave * 512 + 2048]);
      b1[0] = *(const bf16x8*)(Bp0 + kn);
      b1[1] = *(const bf16x8*)(Bp1 + kn);
      b1[2] = *(const bf16x8*)(Bp2 + kn);
      b1[3] = *(const bf16x8*)(Bp3 + kn);
      bf16x8 af[4];
#pragma unroll
      for (int i = 0; i < 4; ++i) af[i] = *(const bf16x8*)&As0[aoff[i]];
#pragma unroll
      for (int i = 0; i < 4; ++i)
#pragma unroll
        for (int j = 0; j < 4; ++j)
          acc[i][j] = __builtin_amdgcn_mfma_f32_16x16x32_bf16(af[i], b0[j], acc[i][j], 0, 0, 0);
      __syncthreads();  // drains As1/b1 prefetch (issued one phase ago) + As0 reads
    }
    // phase 1: compute k0+32 from As1/b1; prefetch k0+64 (dummy 0 on last) -> As0/b0.
    {
      const int kn = (k0 + 64 < K) ? (k0 + 64) : 0;
      load_lds16(Ab1 + kn, &As0[wave * 512]);
      load_lds16(Ab2 + kn, &As0[wave * 512 + 2048]);
      b0[0] = *(const bf16x8*)(Bp0 + kn);
      b0[1] = *(const bf16x8*)(Bp1 + kn);
      b0[2] = *(const bf16x8*)(Bp2 + kn);
      b0[3] = *(const bf16x8*)(Bp3 + kn);
      bf16x8 af[4];
#pragma unroll
      for (int i = 0; i < 4; ++i) af[i] = *(const bf16x8*)&As1[aoff[i]];
#pragma unroll
      for (int i = 0; i < 4; ++i)
#pragma unroll
        for (int j = 0; j < 4; ++j)
          acc[i][j] = __builtin_amdgcn_mfma_f32_16x16x32_bf16(af[i], b1[j], acc[i][j], 0, 0, 0);
      __syncthreads();
    }
  }

#pragma unroll
  for (int i = 0; i < 4; ++i)
#pragma unroll
    for (int j = 0; j < 4; ++j)
#pragma unroll
      for (int r = 0; r < 4; ++r) {
        int m = m0 + wm + i * 16 + quad * 4 + r;
        int n = n0 + wn + j * 16 + colv;
        store_out(C, (size_t)m * N + n, acc[i][j][r]);
      }
}

__global__ __launch_bounds__(256) void gemm_qkv(
    const ushort* __restrict__ A, const ushort* __restrict__ Wq,
    const ushort* __restrict__ Wk, const ushort* __restrict__ Wv,
    ushort* __restrict__ Q, ushort* __restrict__ Kb, ushort* __restrict__ V) {
  const ushort* B = (blockIdx.z == 0) ? Wq : (blockIdx.z == 1) ? Wk : Wv;
  ushort* C = (blockIdx.z == 0) ? Q : (blockIdx.z == 1) ? Kb : V;
  gemm_bt_body<ushort>(A, B, C, 8192, 2048, 2048);
}

__global__ __launch_bounds__(256) void gemm_out_k(
    const ushort* __restrict__ A, const ushort* __restrict__ B,
    float* __restrict__ C) {
  gemm_bt_body<float>(A, B, C, 8192, 2048, 2048);
}

// One kernel converting all five fp32 regions to bf16.
#define NX 4194304u   /* 8192*2048/4 */
#define NW 1048576u   /* 2048*2048/4 */
__global__ void cvt_all(const float* __restrict__ x, const float* __restrict__ wq,
                        const float* __restrict__ wk, const float* __restrict__ wv,
                        const float* __restrict__ wo,
                        ushort* __restrict__ xb, ushort* __restrict__ wqb,
                        ushort* __restrict__ wkb, ushort* __restrict__ wvb,
                        ushort* __restrict__ wob) {
  uint32_t i = blockIdx.x * 256u + threadIdx.x;
  const float* src;
  ushort* dst;
  uint32_t off;
  if (i < NX) {
    src = x; dst = xb; off = i;
  } else {
    uint32_t i2 = i - NX;
    uint32_t r = i2 >> 20;
    off = i2 & (NW - 1u);
    src = (r == 0) ? wq : (r == 1) ? wk : (r == 2) ? wv : wo;
    dst = (r == 0) ? wqb : (r == 1) ? wkb : (r == 2) ? wvb : wob;
  }
  float4 v = ((const float4*)src)[off];
  ushort4 o;
  o.x = f2bf(v.x); o.y = f2bf(v.y); o.z = f2bf(v.z); o.w = f2bf(v.w);
  ((ushort4*)dst)[off] = o;
}

// One block per (b,h). T=128, hd=128. RoPE applied to Q,K on load (fp32 math).
__global__ __launch_bounds__(256) void attn_kernel(
    const ushort* __restrict__ Q, const ushort* __restrict__ K,
    const ushort* __restrict__ V, const float* __restrict__ Cf,
    const float* __restrict__ Sf, ushort* __restrict__ O) {
  __shared__ __align__(16) ushort Qs[128 * 128];   // Q, then P
  __shared__ __align__(16) ushort KVs[128 * 128];  // K, then V^T
  const int b = blockIdx.x >> 4, h = blockIdx.x & 15;
  const int tid = threadIdx.x, wave = tid >> 6, lane = tid & 63;
  const int quad = lane >> 4, colv = lane & 15;
  const size_t gbase = (size_t)b * 262144 + (size_t)h * 128;

#pragma unroll
  for (int sgi = 0; sgi < 8; ++sgi) {
    int seg = tid + sgi * 256;
    int t = seg >> 4, g = seg & 15;
    uint4 qv = *(const uint4*)(Q + gbase + (size_t)t * 2048 + g * 8);
    uint4 kv = *(const uint4*)(K + gbase + (size_t)t * 2048 + g * 8);
    float4 cf = *(const float4*)(Cf + t * 64 + g * 4);
    float4 sf = *(const float4*)(Sf + t * 64 + g * 4);
    uint32_t* qw = (uint32_t*)&qv;
    uint32_t* kw = (uint32_t*)&kv;
#pragma unroll
    for (int j = 0; j < 4; ++j) {
      float c = (&cf.x)[j], s = (&sf.x)[j];
      uint32_t w = qw[j];
      float e = bf2f((ushort)(w & 0xFFFF)), o = bf2f((ushort)(w >> 16));
      qw[j] = (uint32_t)f2bf(e * c - o * s) | ((uint32_t)f2bf(e * s + o * c) << 16);
      w = kw[j];
      e = bf2f((ushort)(w & 0xFFFF)); o = bf2f((ushort)(w >> 16));
      kw[j] = (uint32_t)f2bf(e * c - o * s) | ((uint32_t)f2bf(e * s + o * c) << 16);
    }
    int so = t * 128 + ((g ^ (t & 15)) << 3);
    *(uint4*)&Qs[so] = qv;
    *(uint4*)&KVs[so] = kv;
  }
  __syncthreads();

  floatx4 accs[2][8] = {};
#pragma unroll
  for (int kc = 0; kc < 4; ++kc) {
    bf16x8 af[2], bfr[8];
#pragma unroll
    for (int i = 0; i < 2; ++i) {
      int r = wave * 32 + i * 16 + colv;
      af[i] = *(const bf16x8*)&Qs[r * 128 + ((((kc << 2) | quad) ^ (r & 15)) << 3)];
    }
#pragma unroll
    for (int j = 0; j < 8; ++j) {
      int r = j * 16 + colv;
      bfr[j] = *(const bf16x8*)&KVs[r * 128 + ((((kc << 2) | quad) ^ (r & 15)) << 3)];
    }
#pragma unroll
    for (int i = 0; i < 2; ++i)
#pragma unroll
      for (int j = 0; j < 8; ++j)
        accs[i][j] = __builtin_amdgcn_mfma_f32_16x16x32_bf16(af[i], bfr[j], accs[i][j], 0, 0, 0);
  }

  const float scale = 0.08838834764831845f;  // 1/sqrt(128)
#pragma unroll
  for (int i = 0; i < 2; ++i)
#pragma unroll
    for (int r = 0; r < 4; ++r) {
      int t = wave * 32 + i * 16 + quad * 4 + r;
      float mx = -1e30f;
#pragma unroll
      for (int j = 0; j < 8; ++j) {
        int s = j * 16 + colv;
        float v = accs[i][j][r] * scale;
        v = (s <= t) ? v : -1e30f;
        accs[i][j][r] = v;
        mx = fmaxf(mx, v);
      }
#pragma unroll
      for (int off = 1; off < 16; off <<= 1) mx = fmaxf(mx, __shfl_xor(mx, off, 64));
      float l = 0.f;
#pragma unroll
      for (int j = 0; j < 8; ++j) {
        float p = __expf(accs[i][j][r] - mx);
        accs[i][j][r] = p;
        l += p;
      }
#pragma unroll
      for (int off = 1; off < 16; off <<= 1) l += __shfl_xor(l, off, 64);
      float inv = 1.0f / l;
#pragma unroll
      for (int j = 0; j < 8; ++j) {
        int s = j * 16 + colv;
        Qs[t * 128 + ((((s >> 3) ^ (t & 15)) << 3) | (s & 7))] = f2bf(accs[i][j][r] * inv);
      }
    }
  __syncthreads();

#pragma unroll
  for (int sgi = 0; sgi < 8; ++sgi) {
    int seg = tid + sgi * 256;
    int t = seg >> 4;
    int dg = (seg & 15) << 3;
    uint4 vv = *(const uint4*)(V + gbase + (size_t)t * 2048 + dg);
    const ushort* vp = (const ushort*)&vv;
#pragma unroll
    for (int jj = 0; jj < 8; ++jj) {
      int d = dg + jj;
      KVs[d * 128 + ((((t >> 3) ^ (d & 15)) << 3) | (t & 7))] = vp[jj];
    }
  }
  __syncthreads();

  floatx4 acco[2][8] = {};
#pragma unroll
  for (int kc = 0; kc < 4; ++kc) {
    bf16x8 af[2], bfr[8];
#pragma unroll
    for (int i = 0; i < 2; ++i) {
      int r = wave * 32 + i * 16 + colv;
      af[i] = *(const bf16x8*)&Qs[r * 128 + ((((kc << 2) | quad) ^ (r & 15)) << 3)];
    }
#pragma unroll
    for (int j = 0; j < 8; ++j) {
      int r = j * 16 + colv;
      bfr[j] = *(const bf16x8*)&KVs[r * 128 + ((((kc << 2) | quad) ^ (r & 15)) << 3)];
    }
#pragma unroll
    for (int i = 0; i < 2; ++i)
#pragma unroll
      for (int j = 0; j < 8; ++j)
        acco[i][j] = __builtin_amdgcn_mfma_f32_16x16x32_bf16(af[i], bfr[j], acco[i][j], 0, 0, 0);
  }

#pragma unroll
  for (int i = 0; i < 2; ++i)
#pragma unroll
    for (int j = 0; j < 8; ++j)
#pragma unroll
      for (int r = 0; r < 4; ++r) {
        int t = wave * 32 + i * 16 + quad * 4 + r;
        int d = j * 16 + colv;
        O[gbase + (size_t)t * 2048 + d] = f2bf(acco[i][j][r]);
      }
}

extern "C" void kernel_launch(void* const* d_in, const int* in_sizes, int n_in,
                              void* d_out, int out_size, void* d_ws, size_t ws_size,
                              hipStream_t stream) {
  const float* x    = (const float*)d_in[0];
  const float* fcos = (const float*)d_in[1];
  const float* fsin = (const float*)d_in[2];
  const float* wq   = (const float*)d_in[3];
  const float* wk   = (const float*)d_in[4];
  const float* wv   = (const float*)d_in[5];
  const float* wo   = (const float*)d_in[6];
  float* out = (float*)d_out;

  const size_t CC = 2048ull * 2048ull;
  const size_t MC = 8192ull * 2048ull;
  ushort* wob = (ushort*)d_ws;
  ushort* xb  = wob + CC;
  ushort* wqb = xb + MC;
  ushort* wkb = wqb + CC;
  ushort* wvb = wkb + CC;
  ushort* Qb  = wvb + CC;
  ushort* Kb  = Qb + MC;
  ushort* Vb  = Kb + MC;

  unsigned cvt_blocks = (unsigned)((MC + 4 * CC) / 4 / 256);
  cvt_all<<<dim3(cvt_blocks), 256, 0, stream>>>(x, wq, wk, wv, wo, xb, wqb, wkb, wvb, wob);

  gemm_qkv<<<dim3(64, 16, 3), 256, 0, stream>>>(xb, wqb, wkb, wvb, Qb, Kb, Vb);
  attn_kernel<<<dim3(1024), 256, 0, stream>>>(Qb, Kb, Vb, fcos, fsin, xb);
  gemm_out_k<<<dim3(64, 16), 256, 0, stream>>>(xb, wob, out);
}